// Round 5
// baseline (112.582 us; speedup 1.0000x reference)
//
#include <hip/hip_runtime.h>
#include <hip/hip_bf16.h>
#include <cstdint>

// ---------------- problem constants ----------------
#define BB 1024          // batch
#define DD 512           // dim
#define CC 50000         // classes
#define NTN 782          // ceil(50000/64) n-tiles
#define PSTRIDE 1564     // partials per row = NTN * 2 col-waves
#define NBLK 6256        // 8 m-tiles * 782 n-tiles (= 8*782, XCD-divisible)
#define SCALE_F 64.0f
#define COS_M_F 0.87758256189037276f
#define SIN_M_F 0.47942553860420301f
#define TH_F   (-0.87758256189037276f)
#define MM_F   0.23971276930210156f

typedef __attribute__((ext_vector_type(8))) short short8;
typedef __attribute__((ext_vector_type(8))) unsigned short ushort8;
typedef __attribute__((ext_vector_type(4))) float f32x4;

__device__ __forceinline__ unsigned short f2bf(float x) {
    union { __hip_bfloat16 h; unsigned short u; } v;
    v.h = __float2bfloat16(x);
    return v.u;
}

// ---------------- ws layout (bytes) ----------------
#define OFF_PS   ((size_t)0)                          // [1024][1564] float
#define OFF_LAB  (OFF_PS + (size_t)BB*PSTRIDE*4)      // [1024] float
#define OFF_NLL  (OFF_LAB + 4096)                     // [1024] float
#define OFF_E    (OFF_NLL + 4096)                     // [1024][512] bf16
#define OFF_WBF  (OFF_E + (size_t)BB*DD*2)            // [50000][512] bf16 normalized

// ---------------- kernel 1: normalize embeddings -> bf16 ----------------
__global__ void norm_e_kernel(const float* __restrict__ e, unsigned short* __restrict__ ebf) {
    const int b = blockIdx.x;          // 1024 blocks
    const int l = threadIdx.x;         // 64 threads
    const float4* row = reinterpret_cast<const float4*>(e + (size_t)b * DD);
    float4 v0 = row[l * 2 + 0];
    float4 v1 = row[l * 2 + 1];
    float s = v0.x*v0.x + v0.y*v0.y + v0.z*v0.z + v0.w*v0.w
            + v1.x*v1.x + v1.y*v1.y + v1.z*v1.z + v1.w*v1.w;
    #pragma unroll
    for (int m = 1; m < 64; m <<= 1) s += __shfl_xor(s, m);
    float inv = 1.0f / fmaxf(sqrtf(s), 1e-12f);
    ushort8 h;
    h[0]=f2bf(v0.x*inv); h[1]=f2bf(v0.y*inv); h[2]=f2bf(v0.z*inv); h[3]=f2bf(v0.w*inv);
    h[4]=f2bf(v1.x*inv); h[5]=f2bf(v1.y*inv); h[6]=f2bf(v1.z*inv); h[7]=f2bf(v1.w*inv);
    reinterpret_cast<ushort8*>(ebf + (size_t)b * DD)[l] = h;
}

// ---------------- kernel 2: normalize weights -> bf16 ----------------
__global__ void wnorm_bf16_kernel(const float* __restrict__ w, unsigned short* __restrict__ wbf) {
    const int row = blockIdx.x * 4 + (threadIdx.x >> 6);   // 12500 blocks * 4 waves
    const int l = threadIdx.x & 63;
    const float4* r = reinterpret_cast<const float4*>(w + (size_t)row * DD);
    float4 v0 = r[l * 2 + 0];
    float4 v1 = r[l * 2 + 1];
    float s = v0.x*v0.x + v0.y*v0.y + v0.z*v0.z + v0.w*v0.w
            + v1.x*v1.x + v1.y*v1.y + v1.z*v1.z + v1.w*v1.w;
    #pragma unroll
    for (int m = 1; m < 64; m <<= 1) s += __shfl_xor(s, m);
    float inv = 1.0f / fmaxf(sqrtf(s), 1e-12f);
    ushort8 h;
    h[0]=f2bf(v0.x*inv); h[1]=f2bf(v0.y*inv); h[2]=f2bf(v0.z*inv); h[3]=f2bf(v0.w*inv);
    h[4]=f2bf(v1.x*inv); h[5]=f2bf(v1.y*inv); h[6]=f2bf(v1.z*inv); h[7]=f2bf(v1.w*inv);
    reinterpret_cast<ushort8*>(wbf + (size_t)row * DD)[l] = h;
}

// ---------------- kernel 3: 128x64x64 GEMM + arcface + fixed-max lse ----
// 4 waves (2M x 2N); per-wave 64x32 output (4m x 2n frags of 16x16), acc = 32 VGPR.
// Single-buffered LDS 24 KB (A 16KB @0, B 8KB @16384), 2 barriers/K-iter.
// __launch_bounds__(256,6) -> <=~85 VGPR -> 6 blocks/CU = 24 waves/CU.
__global__ __launch_bounds__(256, 6) void arc_gemm_kernel(
        const unsigned short* __restrict__ ebf,  // [1024][512] bf16 normalized
        const unsigned short* __restrict__ wbf,  // [50000][512] bf16 normalized
        const int* __restrict__ labels,          // [1024]
        float* __restrict__ part_s,              // [1024][1564]
        float* __restrict__ lab_logit)           // [1024]
{
    __shared__ __align__(16) char lds[24576];

    const int t   = threadIdx.x;
    const int wv  = t >> 6;
    const int wr  = wv >> 1;           // row half 0..1 (64 rows)
    const int wc  = wv & 1;            // col half 0..1 (32 cols)
    const int l   = t & 63;
    const int r16 = l & 15;
    const int kg  = l >> 4;

    // XCD-bijective swizzle: 6256 = 8*782; m-tile fastest within an XCD chunk
    const int bid  = blockIdx.x;
    const int bidp = (bid & 7) * NTN + (bid >> 3);
    const int mt = bidp & 7;           // m-tile 0..7
    const int bn = bidp >> 3;          // n-tile 0..781
    const int m0 = mt * 128;
    const int c0 = bn * 64;

    f32x4 acc[4][2];
    #pragma unroll
    for (int m = 0; m < 4; ++m)
        #pragma unroll
        for (int n = 0; n < 2; ++n)
            acc[m][n] = (f32x4){0.f, 0.f, 0.f, 0.f};

    for (int kt = 0; kt < 8; ++kt) {
        // ---- stage A tile [128 rows][64 k] bf16, swizzled src ----
        #pragma unroll
        for (int i = 0; i < 4; ++i) {
            int flat = (i * 256 + t) * 16;
            int row  = flat >> 7;
            int scol = (flat & 127) ^ ((row & 7) << 4);
            const char* src = reinterpret_cast<const char*>(ebf)
                            + (size_t)(m0 + row) * (DD * 2) + kt * 128 + scol;
            __builtin_amdgcn_global_load_lds(
                (const __attribute__((address_space(1))) void*)src,
                (__attribute__((address_space(3))) void*)(&lds[flat]),
                16, 0, 0);
        }
        // ---- stage B tile [64 classes][64 k] bf16 ----
        #pragma unroll
        for (int i = 0; i < 2; ++i) {
            int flat = (i * 256 + t) * 16;
            int row  = flat >> 7;
            int scol = (flat & 127) ^ ((row & 7) << 4);
            int cls  = c0 + row;
            if (cls > CC - 1) cls = CC - 1;    // clamp; masked in epilogue
            const char* src = reinterpret_cast<const char*>(wbf)
                            + (size_t)cls * (DD * 2) + kt * 128 + scol;
            __builtin_amdgcn_global_load_lds(
                (const __attribute__((address_space(1))) void*)src,
                (__attribute__((address_space(3))) void*)(&lds[16384 + flat]),
                16, 0, 0);
        }
        __syncthreads();
        // ---- MFMA ----
        #pragma unroll
        for (int kk = 0; kk < 2; ++kk) {
            const int kb = kk * 64 + kg * 16;
            short8 a[4], b[2];
            #pragma unroll
            for (int m = 0; m < 4; ++m) {
                int row = wr * 64 + m * 16 + r16;
                a[m] = *reinterpret_cast<const short8*>(&lds[row * 128 + (kb ^ ((row & 7) << 4))]);
            }
            #pragma unroll
            for (int n = 0; n < 2; ++n) {
                int row = wc * 32 + n * 16 + r16;
                b[n] = *reinterpret_cast<const short8*>(&lds[16384 + row * 128 + (kb ^ ((row & 7) << 4))]);
            }
            #pragma unroll
            for (int m = 0; m < 4; ++m)
                #pragma unroll
                for (int n = 0; n < 2; ++n)
                    acc[m][n] = __builtin_amdgcn_mfma_f32_16x16x32_bf16(a[m], b[n], acc[m][n], 0, 0, 0);
        }
        __syncthreads();
    }

    // ---- epilogue: fixed-max partial sum of exp(logit - 64) over this wave's 32 cols ----
    #pragma unroll
    for (int m = 0; m < 4; ++m) {
        #pragma unroll
        for (int j = 0; j < 4; ++j) {
            const int rl   = wr * 64 + m * 16 + kg * 4 + j;
            const int grow = m0 + rl;
            const int lab  = labels[grow];
            float s = 0.f;
            #pragma unroll
            for (int n = 0; n < 2; ++n) {
                float cosv = acc[m][n][j];
                int col = c0 + wc * 32 + n * 16 + r16;
                if (col < CC) {
                    float logit = SCALE_F * cosv;
                    if (col == lab) {
                        float c2 = fminf(fmaxf(cosv * cosv, 0.f), 1.f);
                        float phi = cosv * COS_M_F - sqrtf(1.f - c2) * SIN_M_F;
                        phi = (cosv > TH_F) ? phi : (cosv - MM_F);
                        logit = SCALE_F * phi;
                        lab_logit[grow] = logit;
                    }
                    s += __expf(logit - SCALE_F);   // logit <= 64 always
                }
            }
            #pragma unroll
            for (int mk = 1; mk < 16; mk <<= 1) s += __shfl_xor(s, mk);
            if (r16 == 0) {
                part_s[(size_t)grow * PSTRIDE + bn * 2 + wc] = s;
            }
        }
    }
}

// ---------------- kernel 4: per-row sum -> nll (fixed max = 64) ----------------
__global__ void row_lse_kernel(const float* __restrict__ part_s,
                               const float* __restrict__ lab_logit,
                               float* __restrict__ nll) {
    const int row = blockIdx.x;
    const int t = threadIdx.x;   // 256
    const float* ps = part_s + (size_t)row * PSTRIDE;
    float S = 0.f;
    for (int i = t; i < PSTRIDE; i += 256) S += ps[i];
    #pragma unroll
    for (int m = 1; m < 64; m <<= 1) S += __shfl_xor(S, m);
    __shared__ float reds[4];
    if ((t & 63) == 0) reds[t >> 6] = S;
    __syncthreads();
    if (t == 0) {
        float Sf = reds[0] + reds[1] + reds[2] + reds[3];
        // logsumexp = 64 + log(sum exp(l - 64)); nll = -(lab - lse)
        nll[row] = -(lab_logit[row] - SCALE_F - logf(Sf));
    }
}

// ---------------- kernel 5: mean over 1024 -> scalar ----------------
__global__ void mean_kernel(const float* __restrict__ nll, float* __restrict__ out) {
    const int t = threadIdx.x;  // 1024
    float v = nll[t];
    #pragma unroll
    for (int m = 1; m < 64; m <<= 1) v += __shfl_xor(v, m);
    __shared__ float red[16];
    if ((t & 63) == 0) red[t >> 6] = v;
    __syncthreads();
    if (t == 0) {
        float s = 0.f;
        #pragma unroll
        for (int i = 0; i < 16; ++i) s += red[i];
        out[0] = s * (1.0f / BB);
    }
}

// ---------------- launcher ----------------
extern "C" void kernel_launch(void* const* d_in, const int* in_sizes, int n_in,
                              void* d_out, int out_size, void* d_ws, size_t ws_size,
                              hipStream_t stream) {
    const float* emb    = (const float*)d_in[0];
    const int*   labels = (const int*)d_in[1];
    const float* wgt    = (const float*)d_in[2];
    float* out = (float*)d_out;
    char* ws = (char*)d_ws;

    float* ps     = (float*)(ws + OFF_PS);
    float* lablg  = (float*)(ws + OFF_LAB);
    float* nll    = (float*)(ws + OFF_NLL);
    unsigned short* ebf = (unsigned short*)(ws + OFF_E);
    unsigned short* wbf = (unsigned short*)(ws + OFF_WBF);

    norm_e_kernel<<<BB, 64, 0, stream>>>(emb, ebf);
    wnorm_bf16_kernel<<<CC / 4, 256, 0, stream>>>(wgt, wbf);
    arc_gemm_kernel<<<NBLK, 256, 0, stream>>>(ebf, wbf, labels, ps, lablg);
    row_lse_kernel<<<BB, 256, 0, stream>>>(ps, lablg, nll);
    mean_kernel<<<1, 1024, 0, stream>>>(nll, out);
}